// Round 9
// baseline (248.116 us; speedup 1.0000x reference)
//
#include <hip/hip_runtime.h>

namespace {

constexpr int GX = 400, GY = 400;
constexpr int P = 32;
constexpr int K = 60000;
constexpr int MCAP = 128;            // sort capacity per voxel (c_max ~80 « 128)
constexpr int NB = 4;
constexpr int NVOX = NB * GX * GY;   // 640000
constexpr int SCAN_CHUNK = 1024;
constexpr int NBLK = (NVOX + 1 + SCAN_CHUNK - 1) / SCAN_CHUNK;  // 626
constexpr int OCC_PAD = NBLK * SCAN_CHUNK;                      // 641024
constexpr int BW = 512;              // voxel-rank bucket width
constexpr int NBUK = (K + BW - 1) / BW;  // 118
constexpr int PPB = 2048;            // points per k_bucket block

constexpr float XMINf = -20.f, YMINf = -20.f, ZMINf = -2.f;
constexpr float XMAXf =  20.f, YMAXf =  20.f, ZMAXf =  3.f;

constexpr int OUT_CNT = K * P * 4;
constexpr int OUT_COR = OUT_CNT + K;

typedef float floatx2 __attribute__((ext_vector_type(2)));

// DO NOT TOUCH: this exact f32 expression matches the np reference's binning.
__device__ __forceinline__ int bin_of(float v) {
  return (int)((v + 20.0f) * 10.0f);
}

__device__ __forceinline__ bool point_voxel(const float* __restrict__ pt, int& flat) {
  float x = pt[1], y = pt[2], z = pt[3];
  bool m = (x >= XMINf) & (x < XMAXf) & (y >= YMINf) & (y < YMAXf)
         & (z >= ZMINf) & (z < ZMAXf);
  if (!m) return false;
  int bi = (int)pt[0];
  int xi = min(max(bin_of(x), 0), GX - 1);
  int yi = min(max(bin_of(y), 0), GY - 1);
  flat = bi * (GX * GY) + xi * GY + yi;
  return true;
}

// ---- pass 1 (path A): per-flat counts + cached flat ids ------------------
__global__ void k_mark_cnt(const float* __restrict__ pts, int n,
                           int* __restrict__ cntf, int* __restrict__ pflat) {
  int i = blockIdx.x * blockDim.x + threadIdx.x;
  if (i >= n) return;
  int flat = -1;
  if (point_voxel(pts + (size_t)i * 5, flat)) atomicAdd(&cntf[flat], 1);
  pflat[i] = flat;
}

// ---- pass 2a: per-chunk (occupied, count) sums ---------------------------
__global__ void k_bsum2(const int* __restrict__ cntf, int* __restrict__ bsum2) {
  __shared__ int wsO[4], wsC[4];
  int t = threadIdx.x, wid = t >> 6, lane = t & 63;
  int base = blockIdx.x * SCAN_CHUNK;
  int4 v = ((const int4*)(cntf + base))[t];
  int so = (v.x > 0) + (v.y > 0) + (v.z > 0) + (v.w > 0);
  int sc = v.x + v.y + v.z + v.w;
  for (int o = 32; o > 0; o >>= 1) { so += __shfl_xor(so, o, 64); sc += __shfl_xor(sc, o, 64); }
  if (lane == 0) { wsO[wid] = so; wsC[wid] = sc; }
  __syncthreads();
  if (t == 0) {
    bsum2[2 * blockIdx.x]     = wsO[0] + wsO[1] + wsO[2] + wsO[3];
    bsum2[2 * blockIdx.x + 1] = wsC[0] + wsC[1] + wsC[2] + wsC[3];
  }
}

// ---- pass 2b: dual scan of chunk sums (single block) ---------------------
__global__ void k_scanb2(int* __restrict__ bsum2, int* __restrict__ poffR) {
  __shared__ int ldsO[1024], ldsC[1024];
  int t = threadIdx.x;
  int vo = (t < NBLK) ? bsum2[2 * t] : 0;
  int vc = (t < NBLK) ? bsum2[2 * t + 1] : 0;
  ldsO[t] = vo; ldsC[t] = vc;
  __syncthreads();
  for (int o = 1; o < 1024; o <<= 1) {
    int ao = (t >= o) ? ldsO[t - o] : 0;
    int ac = (t >= o) ? ldsC[t - o] : 0;
    __syncthreads();
    ldsO[t] += ao; ldsC[t] += ac;
    __syncthreads();
  }
  if (t < NBLK) { bsum2[2 * t] = ldsO[t] - vo; bsum2[2 * t + 1] = ldsC[t] - vc; }
  if (t == NBLK - 1) {
    int nuq = ldsO[t], tot = ldsC[t];
    bsum2[2 * NBLK] = nuq;
    bsum2[2 * NBLK + 1] = tot;
    if (nuq <= K) poffR[nuq] = tot;
  }
}

// ---- pass 2c: dual wave scan: cntf(counts) -> rank in place; uniq; poffR -
__global__ void k_rank2(int* __restrict__ cntf, const int* __restrict__ bsum2,
                        int* __restrict__ uniq, int* __restrict__ poffR) {
  __shared__ int wsO[4], wsC[4];
  int t = threadIdx.x, wid = t >> 6, lane = t & 63;
  int base = blockIdx.x * SCAN_CHUNK;
  int4 c4 = ((const int4*)(cntf + base))[t];
  int tocc = (c4.x > 0) + (c4.y > 0) + (c4.z > 0) + (c4.w > 0);
  int tcnt = c4.x + c4.y + c4.z + c4.w;
  int so = tocc, sc = tcnt;
  for (int o = 1; o < 64; o <<= 1) {
    int uo = __shfl_up(so, o, 64);
    int uc = __shfl_up(sc, o, 64);
    if (lane >= o) { so += uo; sc += uc; }
  }
  if (lane == 63) { wsO[wid] = so; wsC[wid] = sc; }
  __syncthreads();
  int woffO = 0, woffC = 0;
  for (int w = 0; w < wid; ++w) { woffO += wsO[w]; woffC += wsC[w]; }
  int p  = bsum2[2 * blockIdx.x]     + woffO + (so - tocc);
  int ps = bsum2[2 * blockIdx.x + 1] + woffC + (sc - tcnt);
  int e0 = base + t * 4;
  int4 rk;
  int c;
  c = c4.x; if (c > 0) { if (p < K) { uniq[p] = e0 + 0; poffR[p] = ps; } else if (p == K) poffR[K] = ps; rk.x = p; ++p; } else rk.x = -1; ps += c;
  c = c4.y; if (c > 0) { if (p < K) { uniq[p] = e0 + 1; poffR[p] = ps; } else if (p == K) poffR[K] = ps; rk.y = p; ++p; } else rk.y = -1; ps += c;
  c = c4.z; if (c > 0) { if (p < K) { uniq[p] = e0 + 2; poffR[p] = ps; } else if (p == K) poffR[K] = ps; rk.z = p; ++p; } else rk.z = -1; ps += c;
  c = c4.w; if (c > 0) { if (p < K) { uniq[p] = e0 + 3; poffR[p] = ps; } else if (p == K) poffR[K] = ps; rk.w = p; ++p; } else rk.w = -1; ps += c;
  ((int4*)(cntf + base))[t] = rk;              // cntf now holds rank (or -1)
}

// ---- pass 2e: init bucket cursors to each bucket's global pair base ------
__global__ void k_binit(const int* __restrict__ poffR, const int* __restrict__ nuq_p,
                        int* __restrict__ bcur) {
  int b = blockIdx.x * blockDim.x + threadIdx.x;
  if (b >= NBUK) return;
  int nq = min(nuq_p[0], K);
  bcur[b] = poffR[min(b * BW, nq)];
}

// ---- pass 3: LDS counting-sort points into rank-range buckets ------------
// Each block sorts PPB points by bucket in LDS, then flushes one contiguous
// batch per bucket (single atomic reservation) -> sequential full-line writes.
__global__ void __launch_bounds__(256) k_bucket(
    const int* __restrict__ pflat, const int* __restrict__ rank, int n,
    int* __restrict__ bcur, uint2* __restrict__ pairs) {
  __shared__ unsigned hist[128], sc[128], lbase[128], gbase[128], ofs[128];
  __shared__ uint2 st[PPB];
  __shared__ unsigned tot_s;
  int t = threadIdx.x;
  if (t < 128) hist[t] = 0;
  __syncthreads();

  int base = blockIdx.x * PPB;
  int r[8];
  #pragma unroll
  for (int j = 0; j < 8; ++j) {
    int i = base + j * 256 + t;
    int rr = -1;
    if (i < n) {
      int f = pflat[i];
      if (f >= 0) {
        rr = rank[f];
        if (rr < 0 || rr >= K) rr = -1;
      }
    }
    r[j] = rr;
    if (rr >= 0) atomicAdd(&hist[rr >> 9], 1u);
  }
  __syncthreads();
  if (t < 128) sc[t] = hist[t];
  __syncthreads();
  for (int o = 1; o < 128; o <<= 1) {
    unsigned add = 0;
    if (t < 128 && t >= o) add = sc[t - o];
    __syncthreads();
    if (t < 128) sc[t] += add;
    __syncthreads();
  }
  if (t < 128) { lbase[t] = sc[t] - hist[t]; ofs[t] = sc[t] - hist[t]; }
  if (t == 127) tot_s = sc[127];
  __syncthreads();
  #pragma unroll
  for (int j = 0; j < 8; ++j) {
    if (r[j] >= 0) {
      unsigned pos = atomicAdd(&ofs[r[j] >> 9], 1u);
      st[pos] = make_uint2((unsigned)r[j], (unsigned)(base + j * 256 + t));
    }
  }
  __syncthreads();
  if (t < 128) {
    unsigned nb = hist[t];
    gbase[t] = nb ? (unsigned)atomicAdd(&bcur[t], (int)nb) : 0u;
  }
  __syncthreads();
  unsigned tot = tot_s;
  for (unsigned e = t; e < tot; e += 256) {
    uint2 pr = st[e];
    unsigned b = pr.x >> 9;
    pairs[gbase[b] + (e - lbase[b])] = pr;
  }
}

// ---- pass 4: per-bucket CSR build; one workgroup OWNS one 512-voxel range.
// All scatter confined to that bucket's ~70 KB csr region on one CU/XCD.
__global__ void __launch_bounds__(256) k_build(
    const uint2* __restrict__ pairs, const int* __restrict__ poffR,
    const int* __restrict__ nuq_p, unsigned* __restrict__ csr) {
  __shared__ int cur[BW];
  int b = blockIdx.x;
  int nq = min(nuq_p[0], K);
  int lo = b * BW;
  if (lo >= nq) return;
  int w = min(BW, nq - lo);
  for (int v = threadIdx.x; v < w; v += 256) cur[v] = poffR[lo + v];
  __syncthreads();
  int start = poffR[lo];
  int end = poffR[lo + w];
  for (int j = start + threadIdx.x; j < end; j += 256) {
    uint2 pr = pairs[j];
    int slot = atomicAdd(&cur[(int)pr.x - lo], 1);
    csr[slot] = pr.y;
  }
}

// ---- pass 5: per-voxel contiguous read + bitonic sort + gather + output --
__global__ void __launch_bounds__(256) k_final_csr(
    const float* __restrict__ pts, const unsigned* __restrict__ csr,
    const int* __restrict__ uniq, const int* __restrict__ poffR,
    const int* __restrict__ nuq_p, float* __restrict__ out) {
  int wid = threadIdx.x >> 6, lane = threadIdx.x & 63;
  int k = blockIdx.x * 4 + wid;
  if (k >= K) return;
  int nq = min(nuq_p[0], K);
  int c_tot = 0, c_out = 0, s = 0;
  if (k < nq) {
    s = poffR[k];
    int c = poffR[k + 1] - s;
    c_tot = min(c, MCAP);
    c_out = min(c, P);
  }
  const unsigned UMAX = 0xffffffffu;
  unsigned v0 = (lane < c_tot) ? csr[s + lane] : UMAX;
  unsigned v1 = (lane + 64 < c_tot) ? csr[s + 64 + lane] : UMAX;

  #pragma unroll
  for (int ph = 1; ph <= 7; ++ph) {
    int kk = 1 << ph;
    bool up = ((lane & (kk >> 1)) == 0);
    #pragma unroll
    for (int d = kk >> 1; d >= 2; d >>= 1) {
      int dl = d >> 1;
      unsigned p0 = __shfl_xor(v0, dl, 64);
      unsigned p1 = __shfl_xor(v1, dl, 64);
      bool low = ((lane & dl) == 0);
      if (low == up) { v0 = min(v0, p0); v1 = min(v1, p1); }
      else           { v0 = max(v0, p0); v1 = max(v1, p1); }
    }
    unsigned lo = min(v0, v1), hi = max(v0, v1);
    v0 = up ? lo : hi;
    v1 = up ? hi : lo;
  }

  int mys = lane >> 1, h = lane & 1;
  unsigned a0 = __shfl(v0, mys >> 1, 64);
  unsigned a1 = __shfl(v1, mys >> 1, 64);
  unsigned myidx = (mys & 1) ? a1 : a0;

  float a = 0.f, b = 0.f;
  if (mys < c_out) {
    const float* pp = pts + (size_t)myidx * 5;
    a = pp[1 + 2 * h];
    b = pp[2 + 2 * h];
  }
  floatx2 val = {a, b};
  __builtin_nontemporal_store(val, (floatx2*)(out + (size_t)k * (P * 4)) + lane);

  if (lane == 0) {
    out[OUT_CNT + k] = (float)c_out;
    int f = (k < nq) ? uniq[k] : NVOX;
    int cb = f / (GX * GY), rem = f % (GX * GY);
    out[OUT_COR + (size_t)k * 3 + 0] = (float)cb;
    out[OUT_COR + (size_t)k * 3 + 1] = (float)(rem / GY);
    out[OUT_COR + (size_t)k * 3 + 2] = (float)(rem % GY);
  }
}

// ======== fallback path C (proven R6): candidates voxel-major in d_out ====
__global__ void k_mark(const float* __restrict__ pts, int n,
                       int* __restrict__ occ, int* __restrict__ pflat) {
  int i = blockIdx.x * blockDim.x + threadIdx.x;
  if (i >= n) return;
  int flat = -1;
  if (point_voxel(pts + (size_t)i * 5, flat)) occ[flat] = 1;
  if (pflat) pflat[i] = flat;
}

__global__ void k_bsum(const int* __restrict__ occ, int* __restrict__ bsum) {
  __shared__ int wsums[4];
  int t = threadIdx.x, wid = t >> 6, lane = t & 63;
  int base = blockIdx.x * SCAN_CHUNK;
  int4 v = ((const int4*)(occ + base))[t];
  int s = v.x + v.y + v.z + v.w;
  for (int o = 32; o > 0; o >>= 1) s += __shfl_xor(s, o, 64);
  if (lane == 0) wsums[wid] = s;
  __syncthreads();
  if (t == 0) bsum[blockIdx.x] = wsums[0] + wsums[1] + wsums[2] + wsums[3];
}

__global__ void k_scanb(int* __restrict__ bsum) {
  __shared__ int lds[1024];
  int t = threadIdx.x;
  int v = (t < NBLK) ? bsum[t] : 0;
  lds[t] = v;
  __syncthreads();
  for (int o = 1; o < 1024; o <<= 1) {
    int add = (t >= o) ? lds[t - o] : 0;
    __syncthreads();
    lds[t] += add;
    __syncthreads();
  }
  if (t < NBLK) bsum[t] = lds[t] - v;
  if (t == NBLK - 1) bsum[NBLK] = lds[t];
}

__global__ void k_rank(int* __restrict__ occ, const int* __restrict__ bsum,
                       int* __restrict__ uniq) {
  __shared__ int wsums[4];
  int t = threadIdx.x, wid = t >> 6, lane = t & 63;
  int base = blockIdx.x * SCAN_CHUNK;
  int4 v = ((const int4*)(occ + base))[t];
  int tsum = v.x + v.y + v.z + v.w;
  int sc = tsum;
  for (int o = 1; o < 64; o <<= 1) {
    int u = __shfl_up(sc, o, 64);
    if (lane >= o) sc += u;
  }
  if (lane == 63) wsums[wid] = sc;
  __syncthreads();
  int woff = 0;
  for (int w = 0; w < wid; ++w) woff += wsums[w];
  int p = bsum[blockIdx.x] + woff + (sc - tsum);
  int e0 = base + t * 4;
  int4 r;
  r.x = p; if (v.x) { if (p < K) uniq[p] = e0 + 0; ++p; }
  r.y = p; if (v.y) { if (p < K) uniq[p] = e0 + 1; ++p; }
  r.z = p; if (v.z) { if (p < K) uniq[p] = e0 + 2; ++p; }
  r.w = p; if (v.w) { if (p < K) uniq[p] = e0 + 3; ++p; }
  ((int4*)(occ + base))[t] = r;
}

__global__ void k_append(const int* __restrict__ pflat, int n,
                         const int* __restrict__ rank, int* __restrict__ cnt,
                         unsigned* __restrict__ vox) {
  int i = blockIdx.x * blockDim.x + threadIdx.x;
  if (i >= n) return;
  int f = pflat[i];
  if (f < 0) return;
  int v = rank[f];
  if (v >= K) return;
  int pos = atomicAdd(&cnt[v], 1);
  if (pos < MCAP) vox[(size_t)v * MCAP + pos] = (unsigned)i;
}

__global__ void k_append_fb(const float* __restrict__ pts, int n,
                            const int* __restrict__ rank, int* __restrict__ cnt,
                            unsigned* __restrict__ vox) {
  int i = blockIdx.x * blockDim.x + threadIdx.x;
  if (i >= n) return;
  int flat;
  if (!point_voxel(pts + (size_t)i * 5, flat)) return;
  int v = rank[flat];
  if (v >= K) return;
  int pos = atomicAdd(&cnt[v], 1);
  if (pos < MCAP) vox[(size_t)v * MCAP + pos] = (unsigned)i;
}

__global__ void __launch_bounds__(256) k_final_d(
    const float* __restrict__ pts, const int* __restrict__ uniq,
    const int* __restrict__ cnt, const int* __restrict__ nuq_p,
    float* __restrict__ out) {
  int wid = threadIdx.x >> 6, lane = threadIdx.x & 63;
  int k = blockIdx.x * 4 + wid;
  if (k >= K) return;
  int nuq = min(nuq_p[0], K);
  int c_tot = 0, c_out = 0;
  if (k < nuq) {
    int c = cnt[k];
    c_tot = min(c, MCAP);
    c_out = min(c, P);
  }
  const unsigned UMAX = 0xffffffffu;
  const unsigned* row = (const unsigned*)out + (size_t)k * MCAP;
  uint2 q = ((const uint2*)row)[lane];
  unsigned v0 = (2 * lane     < c_tot) ? q.x : UMAX;
  unsigned v1 = (2 * lane + 1 < c_tot) ? q.y : UMAX;
  #pragma unroll
  for (int ph = 1; ph <= 7; ++ph) {
    int kk = 1 << ph;
    bool up = ((lane & (kk >> 1)) == 0);
    #pragma unroll
    for (int d = kk >> 1; d >= 2; d >>= 1) {
      int dl = d >> 1;
      unsigned p0 = __shfl_xor(v0, dl, 64);
      unsigned p1 = __shfl_xor(v1, dl, 64);
      bool low = ((lane & dl) == 0);
      if (low == up) { v0 = min(v0, p0); v1 = min(v1, p1); }
      else           { v0 = max(v0, p0); v1 = max(v1, p1); }
    }
    unsigned lo = min(v0, v1), hi = max(v0, v1);
    v0 = up ? lo : hi;
    v1 = up ? hi : lo;
  }
  int mys = lane >> 1, h = lane & 1;
  unsigned a0 = __shfl(v0, mys >> 1, 64);
  unsigned a1 = __shfl(v1, mys >> 1, 64);
  unsigned myidx = (mys & 1) ? a1 : a0;
  float a = 0.f, b = 0.f;
  if (mys < c_out) {
    const float* pp = pts + (size_t)myidx * 5;
    a = pp[1 + 2 * h];
    b = pp[2 + 2 * h];
  }
  float2* vout = (float2*)(out + (size_t)k * (P * 4));
  vout[lane] = make_float2(a, b);
  if (lane == 0) {
    out[OUT_CNT + k] = (float)c_out;
    int f = (k < nuq) ? uniq[k] : NVOX;
    int cb = f / (GX * GY), rem = f % (GX * GY);
    out[OUT_COR + (size_t)k * 3 + 0] = (float)cb;
    out[OUT_COR + (size_t)k * 3 + 1] = (float)(rem / GY);
    out[OUT_COR + (size_t)k * 3 + 2] = (float)(rem % GY);
  }
}

}  // namespace

extern "C" void kernel_launch(void* const* d_in, const int* in_sizes, int n_in,
                              void* d_out, int out_size, void* d_ws, size_t ws_size,
                              hipStream_t stream) {
  const float* pts = (const float*)d_in[0];
  int n = in_sizes[0] / 5;
  float* out = (float*)d_out;
  int nb_pts = (n + 255) / 256;

  // ---- path A layout (ints) ----
  size_t o_cntf  = 0;                               // OCC_PAD
  size_t o_bsum2 = o_cntf + OCC_PAD;                // 2*(NBLK+1)
  size_t o_uniq  = o_bsum2 + 2 * (NBLK + 1);        // K
  size_t o_poff  = o_uniq + K;                      // K+1
  size_t o_bcur  = o_poff + K + 1;                  // NBUK
  size_t o_pflat = (o_bcur + NBUK + 3) & ~(size_t)3;// n
  size_t o_pairs = (o_pflat + (size_t)n + 1) & ~(size_t)1;  // 2n (uint2)
  size_t o_csr   = o_pairs + 2 * (size_t)n;         // n
  size_t totA    = o_csr + (size_t)n;

  if (ws_size >= totA * sizeof(int)) {
    int* cntf  = (int*)d_ws + o_cntf;
    int* bsum2 = (int*)d_ws + o_bsum2;
    int* uniq  = (int*)d_ws + o_uniq;
    int* poffR = (int*)d_ws + o_poff;
    int* bcur  = (int*)d_ws + o_bcur;
    int* pflat = (int*)d_ws + o_pflat;
    uint2* pairs = (uint2*)((int*)d_ws + o_pairs);
    unsigned* csr = (unsigned*)((int*)d_ws + o_csr);
    const int* nuq_p = bsum2 + 2 * NBLK;

    hipMemsetAsync(cntf, 0, (size_t)OCC_PAD * sizeof(int), stream);
    k_mark_cnt<<<nb_pts, 256, 0, stream>>>(pts, n, cntf, pflat);
    k_bsum2  <<<NBLK, 256, 0, stream>>>(cntf, bsum2);
    k_scanb2 <<<1, 1024, 0, stream>>>(bsum2, poffR);
    k_rank2  <<<NBLK, 256, 0, stream>>>(cntf, bsum2, uniq, poffR);
    k_binit  <<<(NBUK + 63) / 64, 64, 0, stream>>>(poffR, nuq_p, bcur);
    k_bucket <<<(n + PPB - 1) / PPB, 256, 0, stream>>>(pflat, cntf, n, bcur, pairs);
    k_build  <<<NBUK, 256, 0, stream>>>(pairs, poffR, nuq_p, csr);
    k_final_csr<<<(K + 3) / 4, 256, 0, stream>>>(pts, csr, uniq, poffR, nuq_p, out);
  } else {
    // ---- path C (R6, proven): candidates voxel-major in d_out ----
    int* occ  = (int*)d_ws;
    int* bsum = occ + OCC_PAD;
    int* uniq = bsum + (NBLK + 1);
    int* cnt  = uniq + K;
    size_t base_ints = (size_t)OCC_PAD + (NBLK + 1) + K + K;
    base_ints = (base_ints + 3) & ~(size_t)3;
    int* pflat = (int*)d_ws + base_ints;
    bool use_pflat = ws_size >= (base_ints + (size_t)n) * sizeof(int);

    hipMemsetAsync(occ, 0, (size_t)OCC_PAD * sizeof(int), stream);
    hipMemsetAsync(cnt, 0, (size_t)K * sizeof(int), stream);
    k_mark  <<<nb_pts, 256, 0, stream>>>(pts, n, occ, use_pflat ? pflat : nullptr);
    k_bsum  <<<NBLK, 256, 0, stream>>>(occ, bsum);
    k_scanb <<<1, 1024, 0, stream>>>(bsum);
    k_rank  <<<NBLK, 256, 0, stream>>>(occ, bsum, uniq);
    if (use_pflat)
      k_append<<<nb_pts, 256, 0, stream>>>(pflat, n, occ, cnt, (unsigned*)out);
    else
      k_append_fb<<<nb_pts, 256, 0, stream>>>(pts, n, occ, cnt, (unsigned*)out);
    k_final_d<<<(K + 3) / 4, 256, 0, stream>>>(pts, uniq, cnt, bsum + NBLK, out);
  }
}

// Round 10
// 156.724 us; speedup vs baseline: 1.5831x; 1.5831x over previous
//
#include <hip/hip_runtime.h>

namespace {

constexpr int GX = 400, GY = 400;
constexpr int P = 32;
constexpr int K = 60000;
constexpr int MCAP = 128;
constexpr int NB = 4;
constexpr int NVOX = NB * GX * GY;   // 640000
constexpr int SCAN_CHUNK = 1024;
constexpr int NBLK = (NVOX + 1 + SCAN_CHUNK - 1) / SCAN_CHUNK;  // 626
constexpr int OCC_PAD = NBLK * SCAN_CHUNK;                      // 641024
constexpr int BW = 512;                  // voxel-ranks per bucket
constexpr int NBUK = (K + BW - 1) / BW;  // 118
constexpr int CAPB = 24576;              // bucket arena capacity (mean 17.8k, +51 sigma)
constexpr int PPB = 2048;                // points per k_bucket block

constexpr float XMINf = -20.f, YMINf = -20.f, ZMINf = -2.f;
constexpr float XMAXf =  20.f, YMAXf =  20.f, ZMAXf =  3.f;

constexpr int OUT_CNT = K * P * 4;
constexpr int OUT_COR = OUT_CNT + K;

typedef float floatx2 __attribute__((ext_vector_type(2)));

// DO NOT TOUCH: this exact f32 expression matches the np reference's binning.
__device__ __forceinline__ int bin_of(float v) {
  return (int)((v + 20.0f) * 10.0f);
}

__device__ __forceinline__ bool point_voxel(const float* __restrict__ pt, int& flat) {
  float x = pt[1], y = pt[2], z = pt[3];
  bool m = (x >= XMINf) & (x < XMAXf) & (y >= YMINf) & (y < YMAXf)
         & (z >= ZMINf) & (z < ZMAXf);
  if (!m) return false;
  int bi = (int)pt[0];
  int xi = min(max(bin_of(x), 0), GX - 1);
  int yi = min(max(bin_of(y), 0), GY - 1);
  flat = bi * (GX * GY) + xi * GY + yi;
  return true;
}

// ---- pass 1: occupancy flags (plain stores - NO atomics) + cached flats --
__global__ void k_mark(const float* __restrict__ pts, int n,
                       int* __restrict__ occ, int* __restrict__ pflat) {
  int i = blockIdx.x * blockDim.x + threadIdx.x;
  if (i >= n) return;
  int flat = -1;
  if (point_voxel(pts + (size_t)i * 5, flat)) occ[flat] = 1;  // benign race
  if (pflat) pflat[i] = flat;
}

// ---- pass 2a: per-chunk occupancy sums -----------------------------------
__global__ void k_bsum(const int* __restrict__ occ, int* __restrict__ bsum) {
  __shared__ int wsums[4];
  int t = threadIdx.x, wid = t >> 6, lane = t & 63;
  int base = blockIdx.x * SCAN_CHUNK;
  int4 v = ((const int4*)(occ + base))[t];
  int s = v.x + v.y + v.z + v.w;
  for (int o = 32; o > 0; o >>= 1) s += __shfl_xor(s, o, 64);
  if (lane == 0) wsums[wid] = s;
  __syncthreads();
  if (t == 0) bsum[blockIdx.x] = wsums[0] + wsums[1] + wsums[2] + wsums[3];
}

// ---- pass 2b: scan chunk sums (single block) -----------------------------
__global__ void k_scanb(int* __restrict__ bsum) {
  __shared__ int lds[1024];
  int t = threadIdx.x;
  int v = (t < NBLK) ? bsum[t] : 0;
  lds[t] = v;
  __syncthreads();
  for (int o = 1; o < 1024; o <<= 1) {
    int add = (t >= o) ? lds[t - o] : 0;
    __syncthreads();
    lds[t] += add;
    __syncthreads();
  }
  if (t < NBLK) bsum[t] = lds[t] - v;
  if (t == NBLK - 1) bsum[NBLK] = lds[t];         // num_unique
}

// ---- pass 2c: occ -> rank in place; emit uniq ----------------------------
__global__ void k_rank(int* __restrict__ occ, const int* __restrict__ bsum,
                       int* __restrict__ uniq) {
  __shared__ int wsums[4];
  int t = threadIdx.x, wid = t >> 6, lane = t & 63;
  int base = blockIdx.x * SCAN_CHUNK;
  int4 v = ((const int4*)(occ + base))[t];
  int tsum = v.x + v.y + v.z + v.w;
  int sc = tsum;
  for (int o = 1; o < 64; o <<= 1) {
    int u = __shfl_up(sc, o, 64);
    if (lane >= o) sc += u;
  }
  if (lane == 63) wsums[wid] = sc;
  __syncthreads();
  int woff = 0;
  for (int w = 0; w < wid; ++w) woff += wsums[w];
  int p = bsum[blockIdx.x] + woff + (sc - tsum);
  int e0 = base + t * 4;
  int4 r;
  r.x = p; if (v.x) { if (p < K) uniq[p] = e0 + 0; ++p; }
  r.y = p; if (v.y) { if (p < K) uniq[p] = e0 + 1; ++p; }
  r.z = p; if (v.z) { if (p < K) uniq[p] = e0 + 2; ++p; }
  r.w = p; if (v.w) { if (p < K) uniq[p] = e0 + 3; ++p; }
  ((int4*)(occ + base))[t] = r;
}

// ---- pass 3: LDS counting-sort points into 118 rank-range buckets --------
// Folds the rank gather (was k_remap). Flushes one contiguous batch per
// (block,bucket) into fixed-capacity arenas: 1 reservation atomic per batch,
// sequential full-line writes. Packs (rank&511)<<21 | idx  (idx < 2^21).
__global__ void __launch_bounds__(256) k_bucket(
    const int* __restrict__ pflat, const int* __restrict__ rank, int n,
    int* __restrict__ bcur, unsigned* __restrict__ pairs) {
  __shared__ unsigned hist[128], sc[128], lbase[128], gbase[128], ofs[128];
  __shared__ uint2 st[PPB];
  __shared__ unsigned tot_s;
  int t = threadIdx.x;
  if (t < 128) hist[t] = 0;
  __syncthreads();

  int base = blockIdx.x * PPB;
  int r[8];
  #pragma unroll
  for (int j = 0; j < 8; ++j) {
    int i = base + j * 256 + t;
    int rr = -1;
    if (i < n) {
      int f = pflat[i];
      if (f >= 0) {
        rr = rank[f];
        if (rr < 0 || rr >= K) rr = -1;
      }
    }
    r[j] = rr;
    if (rr >= 0) atomicAdd(&hist[rr >> 9], 1u);
  }
  __syncthreads();
  if (t < 128) sc[t] = hist[t];
  __syncthreads();
  for (int o = 1; o < 128; o <<= 1) {
    unsigned add = 0;
    if (t < 128 && t >= o) add = sc[t - o];
    __syncthreads();
    if (t < 128) sc[t] += add;
    __syncthreads();
  }
  if (t < 128) { lbase[t] = sc[t] - hist[t]; ofs[t] = sc[t] - hist[t]; }
  if (t == 127) tot_s = sc[127];
  __syncthreads();
  #pragma unroll
  for (int j = 0; j < 8; ++j) {
    if (r[j] >= 0) {
      unsigned pos = atomicAdd(&ofs[r[j] >> 9], 1u);
      st[pos] = make_uint2((unsigned)r[j], (unsigned)(base + j * 256 + t));
    }
  }
  __syncthreads();
  if (t < 128) {
    unsigned nb = hist[t];
    gbase[t] = nb ? (unsigned)atomicAdd(&bcur[t], (int)nb) : 0u;
  }
  __syncthreads();
  unsigned tot = tot_s;
  for (unsigned e = t; e < tot; e += 256) {
    uint2 pr = st[e];
    unsigned b = pr.x >> 9;
    unsigned dst = gbase[b] + (e - lbase[b]);
    if (dst < CAPB)
      pairs[(size_t)b * CAPB + dst] = ((pr.x & 511u) << 21) | pr.y;
  }
}

// ---- pass 4: per-bucket CSR build. One block OWNS one bucket: LDS stage,
// local hist+scan -> per-voxel offsets, scatter within own arena ----------
__global__ void __launch_bounds__(256) k_build(
    const unsigned* __restrict__ pairs, const int* __restrict__ bcur,
    const int* __restrict__ nuq_p, unsigned* __restrict__ csr,
    int* __restrict__ voxoff, int* __restrict__ vcnt) {
  __shared__ unsigned st[CAPB];                    // 96 KB
  __shared__ int hist[BW], scn[BW], cur[BW];
  __shared__ int ps[256];
  int b = blockIdx.x, t = threadIdx.x;
  int nq = min(nuq_p[0], K);
  int lo = b * BW;
  if (lo >= nq) return;
  int w = min(BW, nq - lo);
  int tot = min(bcur[b], CAPB);
  for (int v = t; v < BW; v += 256) hist[v] = 0;
  __syncthreads();
  const unsigned* pb = pairs + (size_t)b * CAPB;
  for (int j = t; j < tot; j += 256) {             // stage + histogram
    unsigned pr = pb[j];
    st[j] = pr;
    atomicAdd(&hist[pr >> 21], 1);
  }
  __syncthreads();
  int h0 = hist[2 * t], h1 = hist[2 * t + 1];      // scan 512 bins
  ps[t] = h0 + h1;
  __syncthreads();
  for (int o = 1; o < 256; o <<= 1) {
    int add = (t >= o) ? ps[t - o] : 0;
    __syncthreads();
    ps[t] += add;
    __syncthreads();
  }
  int excl = ps[t] - (h0 + h1);
  scn[2 * t] = excl;          scn[2 * t + 1] = excl + h0;
  cur[2 * t] = excl;          cur[2 * t + 1] = excl + h0;
  __syncthreads();
  unsigned cbase = (unsigned)b * CAPB;
  for (int j = t; j < tot; j += 256) {             // scatter into own arena
    unsigned pr = st[j];
    int slot = atomicAdd(&cur[pr >> 21], 1);
    csr[cbase + slot] = pr & 0x1FFFFFu;
  }
  for (int v = t; v < w; v += 256) {
    voxoff[lo + v] = (int)cbase + scn[v];
    vcnt[lo + v] = hist[v];
  }
}

// ---- pass 5: contiguous candidate read + bitonic sort + gather + output --
__global__ void __launch_bounds__(256) k_final_csr(
    const float* __restrict__ pts, const unsigned* __restrict__ csr,
    const int* __restrict__ uniq, const int* __restrict__ voxoff,
    const int* __restrict__ vcnt, const int* __restrict__ nuq_p,
    float* __restrict__ out) {
  int wid = threadIdx.x >> 6, lane = threadIdx.x & 63;
  int k = blockIdx.x * 4 + wid;
  if (k >= K) return;
  int nq = min(nuq_p[0], K);
  int c_tot = 0, c_out = 0, s = 0;
  if (k < nq) {
    s = voxoff[k];
    int c = vcnt[k];
    c_tot = min(c, MCAP);
    c_out = min(c, P);
  }
  const unsigned UMAX = 0xffffffffu;
  unsigned v0 = (lane < c_tot) ? csr[s + lane] : UMAX;
  unsigned v1 = (lane + 64 < c_tot) ? csr[s + 64 + lane] : UMAX;

  #pragma unroll
  for (int ph = 1; ph <= 7; ++ph) {
    int kk = 1 << ph;
    bool up = ((lane & (kk >> 1)) == 0);
    #pragma unroll
    for (int d = kk >> 1; d >= 2; d >>= 1) {
      int dl = d >> 1;
      unsigned p0 = __shfl_xor(v0, dl, 64);
      unsigned p1 = __shfl_xor(v1, dl, 64);
      bool low = ((lane & dl) == 0);
      if (low == up) { v0 = min(v0, p0); v1 = min(v1, p1); }
      else           { v0 = max(v0, p0); v1 = max(v1, p1); }
    }
    unsigned lo = min(v0, v1), hi = max(v0, v1);
    v0 = up ? lo : hi;
    v1 = up ? hi : lo;
  }

  int mys = lane >> 1, h = lane & 1;
  unsigned a0 = __shfl(v0, mys >> 1, 64);
  unsigned a1 = __shfl(v1, mys >> 1, 64);
  unsigned myidx = (mys & 1) ? a1 : a0;

  float a = 0.f, b = 0.f;
  if (mys < c_out) {
    const float* pp = pts + (size_t)myidx * 5;
    a = pp[1 + 2 * h];
    b = pp[2 + 2 * h];
  }
  floatx2 val = {a, b};
  __builtin_nontemporal_store(val, (floatx2*)(out + (size_t)k * (P * 4)) + lane);

  if (lane == 0) {
    out[OUT_CNT + k] = (float)c_out;
    int f = (k < nq) ? uniq[k] : NVOX;
    int cb = f / (GX * GY), rem = f % (GX * GY);
    out[OUT_COR + (size_t)k * 3 + 0] = (float)cb;
    out[OUT_COR + (size_t)k * 3 + 1] = (float)(rem / GY);
    out[OUT_COR + (size_t)k * 3 + 2] = (float)(rem % GY);
  }
}

// ======== fallback path C (proven R6): candidates voxel-major in d_out ====
__global__ void k_append(const int* __restrict__ pflat, int n,
                         const int* __restrict__ rank, int* __restrict__ cnt,
                         unsigned* __restrict__ vox) {
  int i = blockIdx.x * blockDim.x + threadIdx.x;
  if (i >= n) return;
  int f = pflat[i];
  if (f < 0) return;
  int v = rank[f];
  if (v >= K) return;
  int pos = atomicAdd(&cnt[v], 1);
  if (pos < MCAP) vox[(size_t)v * MCAP + pos] = (unsigned)i;
}

__global__ void k_append_fb(const float* __restrict__ pts, int n,
                            const int* __restrict__ rank, int* __restrict__ cnt,
                            unsigned* __restrict__ vox) {
  int i = blockIdx.x * blockDim.x + threadIdx.x;
  if (i >= n) return;
  int flat;
  if (!point_voxel(pts + (size_t)i * 5, flat)) return;
  int v = rank[flat];
  if (v >= K) return;
  int pos = atomicAdd(&cnt[v], 1);
  if (pos < MCAP) vox[(size_t)v * MCAP + pos] = (unsigned)i;
}

__global__ void __launch_bounds__(256) k_final_d(
    const float* __restrict__ pts, const int* __restrict__ uniq,
    const int* __restrict__ cnt, const int* __restrict__ nuq_p,
    float* __restrict__ out) {
  int wid = threadIdx.x >> 6, lane = threadIdx.x & 63;
  int k = blockIdx.x * 4 + wid;
  if (k >= K) return;
  int nuq = min(nuq_p[0], K);
  int c_tot = 0, c_out = 0;
  if (k < nuq) {
    int c = cnt[k];
    c_tot = min(c, MCAP);
    c_out = min(c, P);
  }
  const unsigned UMAX = 0xffffffffu;
  const unsigned* row = (const unsigned*)out + (size_t)k * MCAP;
  uint2 q = ((const uint2*)row)[lane];
  unsigned v0 = (2 * lane     < c_tot) ? q.x : UMAX;
  unsigned v1 = (2 * lane + 1 < c_tot) ? q.y : UMAX;
  #pragma unroll
  for (int ph = 1; ph <= 7; ++ph) {
    int kk = 1 << ph;
    bool up = ((lane & (kk >> 1)) == 0);
    #pragma unroll
    for (int d = kk >> 1; d >= 2; d >>= 1) {
      int dl = d >> 1;
      unsigned p0 = __shfl_xor(v0, dl, 64);
      unsigned p1 = __shfl_xor(v1, dl, 64);
      bool low = ((lane & dl) == 0);
      if (low == up) { v0 = min(v0, p0); v1 = min(v1, p1); }
      else           { v0 = max(v0, p0); v1 = max(v1, p1); }
    }
    unsigned lo = min(v0, v1), hi = max(v0, v1);
    v0 = up ? lo : hi;
    v1 = up ? hi : lo;
  }
  int mys = lane >> 1, h = lane & 1;
  unsigned a0 = __shfl(v0, mys >> 1, 64);
  unsigned a1 = __shfl(v1, mys >> 1, 64);
  unsigned myidx = (mys & 1) ? a1 : a0;
  float a = 0.f, b = 0.f;
  if (mys < c_out) {
    const float* pp = pts + (size_t)myidx * 5;
    a = pp[1 + 2 * h];
    b = pp[2 + 2 * h];
  }
  float2* vout = (float2*)(out + (size_t)k * (P * 4));
  vout[lane] = make_float2(a, b);
  if (lane == 0) {
    out[OUT_CNT + k] = (float)c_out;
    int f = (k < nuq) ? uniq[k] : NVOX;
    int cb = f / (GX * GY), rem = f % (GX * GY);
    out[OUT_COR + (size_t)k * 3 + 0] = (float)cb;
    out[OUT_COR + (size_t)k * 3 + 1] = (float)(rem / GY);
    out[OUT_COR + (size_t)k * 3 + 2] = (float)(rem % GY);
  }
}

}  // namespace

extern "C" void kernel_launch(void* const* d_in, const int* in_sizes, int n_in,
                              void* d_out, int out_size, void* d_ws, size_t ws_size,
                              hipStream_t stream) {
  const float* pts = (const float*)d_in[0];
  int n = in_sizes[0] / 5;
  float* out = (float*)d_out;
  int nb_pts = (n + 255) / 256;

  // ---- path A layout (ints) ----
  size_t o_occ   = 0;                                // OCC_PAD (becomes rank)
  size_t o_bsum  = o_occ + OCC_PAD;                  // NBLK+1
  size_t o_uniq  = o_bsum + NBLK + 1;                // K
  size_t o_voff  = o_uniq + K;                       // K
  size_t o_vcnt  = o_voff + K;                       // K
  size_t o_bcur  = o_vcnt + K;                       // NBUK
  size_t o_pflat = (o_bcur + NBUK + 3) & ~(size_t)3; // n
  size_t o_pairs = (o_pflat + (size_t)n + 3) & ~(size_t)3;  // NBUK*CAPB
  size_t o_csr   = o_pairs + (size_t)NBUK * CAPB;    // NBUK*CAPB
  size_t totA    = o_csr + (size_t)NBUK * CAPB;

  if (ws_size >= totA * sizeof(int) && n <= (1 << 21)) {
    int* occ   = (int*)d_ws + o_occ;
    int* bsum  = (int*)d_ws + o_bsum;
    int* uniq  = (int*)d_ws + o_uniq;
    int* voff  = (int*)d_ws + o_voff;
    int* vcnt  = (int*)d_ws + o_vcnt;
    int* bcur  = (int*)d_ws + o_bcur;
    int* pflat = (int*)d_ws + o_pflat;
    unsigned* pairs = (unsigned*)((int*)d_ws + o_pairs);
    unsigned* csr   = (unsigned*)((int*)d_ws + o_csr);
    const int* nuq_p = bsum + NBLK;

    hipMemsetAsync(occ, 0, (size_t)OCC_PAD * sizeof(int), stream);
    hipMemsetAsync(bcur, 0, (size_t)NBUK * sizeof(int), stream);
    k_mark  <<<nb_pts, 256, 0, stream>>>(pts, n, occ, pflat);
    k_bsum  <<<NBLK, 256, 0, stream>>>(occ, bsum);
    k_scanb <<<1, 1024, 0, stream>>>(bsum);
    k_rank  <<<NBLK, 256, 0, stream>>>(occ, bsum, uniq);
    k_bucket<<<(n + PPB - 1) / PPB, 256, 0, stream>>>(pflat, occ, n, bcur, pairs);
    k_build <<<NBUK, 256, 0, stream>>>(pairs, bcur, nuq_p, csr, voff, vcnt);
    k_final_csr<<<(K + 3) / 4, 256, 0, stream>>>(pts, csr, uniq, voff, vcnt, nuq_p, out);
  } else {
    // ---- path C (R6, proven): candidates voxel-major in d_out ----
    int* occ  = (int*)d_ws;
    int* bsum = occ + OCC_PAD;
    int* uniq = bsum + (NBLK + 1);
    int* cnt  = uniq + K;
    size_t base_ints = (size_t)OCC_PAD + (NBLK + 1) + K + K;
    base_ints = (base_ints + 3) & ~(size_t)3;
    int* pflat = (int*)d_ws + base_ints;
    bool use_pflat = ws_size >= (base_ints + (size_t)n) * sizeof(int);

    hipMemsetAsync(occ, 0, (size_t)OCC_PAD * sizeof(int), stream);
    hipMemsetAsync(cnt, 0, (size_t)K * sizeof(int), stream);
    k_mark  <<<nb_pts, 256, 0, stream>>>(pts, n, occ, use_pflat ? pflat : nullptr);
    k_bsum  <<<NBLK, 256, 0, stream>>>(occ, bsum);
    k_scanb <<<1, 1024, 0, stream>>>(bsum);
    k_rank  <<<NBLK, 256, 0, stream>>>(occ, bsum, uniq);
    if (use_pflat)
      k_append<<<nb_pts, 256, 0, stream>>>(pflat, n, occ, cnt, (unsigned*)out);
    else
      k_append_fb<<<nb_pts, 256, 0, stream>>>(pts, n, occ, cnt, (unsigned*)out);
    k_final_d<<<(K + 3) / 4, 256, 0, stream>>>(pts, uniq, cnt, bsum + NBLK, out);
  }
}

// Round 11
// 136.980 us; speedup vs baseline: 1.8113x; 1.1441x over previous
//
#include <hip/hip_runtime.h>

namespace {

constexpr int GX = 400, GY = 400;
constexpr int P = 32;
constexpr int K = 60000;
constexpr int MCAP = 128;
constexpr int NB = 4;
constexpr int NVOX = NB * GX * GY;   // 640000
constexpr int SCAN_CHUNK = 1024;
constexpr int NBLK = (NVOX + 1 + SCAN_CHUNK - 1) / SCAN_CHUNK;  // 626
constexpr int OCC_PAD = NBLK * SCAN_CHUNK;                      // 641024
constexpr int BW2 = 1024;                // flats per bucket
constexpr int NBUK2 = NVOX / BW2;        // 625
constexpr int NBH = 768;                 // padded hist (3 bins/thread in K1)
constexpr int CAPB2 = 14336;             // arena capacity (mean ~10.6k, +36 sigma)
constexpr int PPB = 2048;                // points per K1 block

constexpr float XMINf = -20.f, YMINf = -20.f, ZMINf = -2.f;
constexpr float XMAXf =  20.f, YMAXf =  20.f, ZMAXf =  3.f;

constexpr int OUT_CNT = K * P * 4;
constexpr int OUT_COR = OUT_CNT + K;

typedef float floatx2 __attribute__((ext_vector_type(2)));

// DO NOT TOUCH: this exact f32 expression matches the np reference's binning.
__device__ __forceinline__ int bin_of(float v) {
  return (int)((v + 20.0f) * 10.0f);
}

__device__ __forceinline__ bool point_voxel(const float* __restrict__ pt, int& flat) {
  float x = pt[1], y = pt[2], z = pt[3];
  bool m = (x >= XMINf) & (x < XMAXf) & (y >= YMINf) & (y < YMAXf)
         & (z >= ZMINf) & (z < ZMAXf);
  if (!m) return false;
  int bi = (int)pt[0];
  int xi = min(max(bin_of(x), 0), GX - 1);
  int yi = min(max(bin_of(y), 0), GY - 1);
  flat = bi * (GX * GY) + xi * GY + yi;
  return true;
}

// ---- pass 1 (fused): read pts, mark occ, LDS-countsort into 625 flat-range
// buckets, flush packed (flat&1023)<<21|idx records to fixed arenas ---------
__global__ void __launch_bounds__(256) k_mark_bucket(
    const float* __restrict__ pts, int n, int* __restrict__ occ,
    int* __restrict__ bcur, unsigned* __restrict__ arena) {
  __shared__ unsigned hist[NBH], lbase[NBH], gbase[NBH], ofs[NBH];
  __shared__ unsigned st[PPB];
  __shared__ unsigned short stb[PPB];
  __shared__ unsigned ps[256];
  __shared__ unsigned tot_s;
  int t = threadIdx.x;
  for (int j = t; j < NBH; j += 256) hist[j] = 0;
  __syncthreads();

  int base = blockIdx.x * PPB;
  int bk[8]; unsigned rec[8];
  #pragma unroll
  for (int j = 0; j < 8; ++j) {
    int i = base + j * 256 + t;
    bk[j] = -1;
    if (i < n) {
      int flat;
      if (point_voxel(pts + (size_t)i * 5, flat)) {
        occ[flat] = 1;                          // benign race, plain store
        bk[j] = flat >> 10;
        rec[j] = ((unsigned)(flat & 1023) << 21) | (unsigned)i;
      }
    }
    if (bk[j] >= 0) atomicAdd(&hist[bk[j]], 1u);
  }
  __syncthreads();
  // scan 768 bins, 3 contiguous bins per thread
  unsigned h0 = hist[3 * t], h1 = hist[3 * t + 1], h2 = hist[3 * t + 2];
  unsigned local = h0 + h1 + h2;
  ps[t] = local;
  __syncthreads();
  for (int o = 1; o < 256; o <<= 1) {
    unsigned add = (t >= o) ? ps[t - o] : 0;
    __syncthreads();
    ps[t] += add;
    __syncthreads();
  }
  unsigned excl = ps[t] - local;
  lbase[3 * t] = excl;            ofs[3 * t] = excl;
  lbase[3 * t + 1] = excl + h0;   ofs[3 * t + 1] = excl + h0;
  lbase[3 * t + 2] = excl + h0 + h1; ofs[3 * t + 2] = excl + h0 + h1;
  if (t == 255) tot_s = ps[255];
  __syncthreads();
  #pragma unroll
  for (int j = 0; j < 8; ++j) {
    if (bk[j] >= 0) {
      unsigned pos = atomicAdd(&ofs[bk[j]], 1u);
      st[pos] = rec[j];
      stb[pos] = (unsigned short)bk[j];
    }
  }
  __syncthreads();
  for (int b = t; b < NBUK2; b += 256) {       // one reservation per bucket
    unsigned nb = hist[b];
    gbase[b] = nb ? (unsigned)atomicAdd(&bcur[b], (int)nb) : 0u;
  }
  __syncthreads();
  unsigned tot = tot_s;
  for (unsigned e = t; e < tot; e += 256) {    // contiguous batch flush
    unsigned b = stb[e];
    unsigned dst = gbase[b] + (e - lbase[b]);
    if (dst < CAPB2) arena[(size_t)b * CAPB2 + dst] = st[e];
  }
}

// ---- pass 2a/2b/2c: occupancy scan chain (proven) ------------------------
__global__ void k_bsum(const int* __restrict__ occ, int* __restrict__ bsum) {
  __shared__ int wsums[4];
  int t = threadIdx.x, wid = t >> 6, lane = t & 63;
  int base = blockIdx.x * SCAN_CHUNK;
  int4 v = ((const int4*)(occ + base))[t];
  int s = v.x + v.y + v.z + v.w;
  for (int o = 32; o > 0; o >>= 1) s += __shfl_xor(s, o, 64);
  if (lane == 0) wsums[wid] = s;
  __syncthreads();
  if (t == 0) bsum[blockIdx.x] = wsums[0] + wsums[1] + wsums[2] + wsums[3];
}

__global__ void k_scanb(int* __restrict__ bsum) {
  __shared__ int lds[1024];
  int t = threadIdx.x;
  int v = (t < NBLK) ? bsum[t] : 0;
  lds[t] = v;
  __syncthreads();
  for (int o = 1; o < 1024; o <<= 1) {
    int add = (t >= o) ? lds[t - o] : 0;
    __syncthreads();
    lds[t] += add;
    __syncthreads();
  }
  if (t < NBLK) bsum[t] = lds[t] - v;
  if (t == NBLK - 1) bsum[NBLK] = lds[t];         // num_unique
}

__global__ void k_rank(int* __restrict__ occ, const int* __restrict__ bsum,
                       int* __restrict__ uniq) {
  __shared__ int wsums[4];
  int t = threadIdx.x, wid = t >> 6, lane = t & 63;
  int base = blockIdx.x * SCAN_CHUNK;
  int4 v = ((const int4*)(occ + base))[t];
  int tsum = v.x + v.y + v.z + v.w;
  int sc = tsum;
  for (int o = 1; o < 64; o <<= 1) {
    int u = __shfl_up(sc, o, 64);
    if (lane >= o) sc += u;
  }
  if (lane == 63) wsums[wid] = sc;
  __syncthreads();
  int woff = 0;
  for (int w = 0; w < wid; ++w) woff += wsums[w];
  int p = bsum[blockIdx.x] + woff + (sc - tsum);
  int e0 = base + t * 4;
  int4 r;
  r.x = p; if (v.x) { if (p < K) uniq[p] = e0 + 0; ++p; }
  r.y = p; if (v.y) { if (p < K) uniq[p] = e0 + 1; ++p; }
  r.z = p; if (v.z) { if (p < K) uniq[p] = e0 + 2; ++p; }
  r.w = p; if (v.w) { if (p < K) uniq[p] = e0 + 3; ++p; }
  ((int4*)(occ + base))[t] = r;
}

// ---- pass 3: per-bucket CSR build IN-PLACE in the arena ------------------
// One block owns one bucket: stage records in LDS, 1024-bin hist+scan, load
// the bucket's rank slice, scatter csr back into own arena segment.
__global__ void __launch_bounds__(256) k_build(
    unsigned* __restrict__ arena, const int* __restrict__ bcur,
    const int* __restrict__ rank, int* __restrict__ voxoff,
    int* __restrict__ vcnt) {
  __shared__ unsigned st[CAPB2];                 // 56 KB
  __shared__ int hist[BW2], scn[BW2], cur[BW2], rk[BW2];
  __shared__ int ps[256];
  int b = blockIdx.x, t = threadIdx.x;
  int tot = min(bcur[b], CAPB2);
  for (int f = t; f < BW2; f += 256) hist[f] = 0;
  __syncthreads();
  unsigned* pb = arena + (size_t)b * CAPB2;
  for (int j = t; j < tot; j += 256) {           // stage + histogram
    unsigned r = pb[j];
    st[j] = r;
    atomicAdd(&hist[r >> 21], 1);
  }
  for (int f = t; f < BW2; f += 256) rk[f] = rank[b * BW2 + f];
  __syncthreads();
  int h0 = hist[4 * t], h1 = hist[4 * t + 1], h2 = hist[4 * t + 2], h3 = hist[4 * t + 3];
  int local = h0 + h1 + h2 + h3;
  ps[t] = local;
  __syncthreads();
  for (int o = 1; o < 256; o <<= 1) {
    int add = (t >= o) ? ps[t - o] : 0;
    __syncthreads();
    ps[t] += add;
    __syncthreads();
  }
  int excl = ps[t] - local;
  scn[4 * t] = excl;                cur[4 * t] = excl;
  scn[4 * t + 1] = excl + h0;       cur[4 * t + 1] = excl + h0;
  scn[4 * t + 2] = excl + h0 + h1;  cur[4 * t + 2] = excl + h0 + h1;
  scn[4 * t + 3] = excl + h0 + h1 + h2; cur[4 * t + 3] = excl + h0 + h1 + h2;
  __syncthreads();
  int cbase = b * CAPB2;
  for (int j = t; j < tot; j += 256) {           // in-place csr scatter
    unsigned r = st[j];
    int slot = atomicAdd(&cur[r >> 21], 1);
    pb[slot] = r & 0x1FFFFFu;
  }
  for (int f = t; f < BW2; f += 256) {
    if (hist[f] > 0) {
      int rr = rk[f];
      if (rr >= 0 && rr < K) { voxoff[rr] = cbase + scn[f]; vcnt[rr] = hist[f]; }
    }
  }
}

// ---- pass 4: contiguous candidate read + bitonic sort + gather + output --
__global__ void __launch_bounds__(256) k_final_csr(
    const float* __restrict__ pts, const unsigned* __restrict__ csr,
    const int* __restrict__ uniq, const int* __restrict__ voxoff,
    const int* __restrict__ vcnt, const int* __restrict__ nuq_p,
    float* __restrict__ out) {
  int wid = threadIdx.x >> 6, lane = threadIdx.x & 63;
  int k = blockIdx.x * 4 + wid;
  if (k >= K) return;
  int nq = min(nuq_p[0], K);
  int c_tot = 0, c_out = 0, s = 0;
  if (k < nq) {
    s = voxoff[k];
    int c = vcnt[k];
    c_tot = min(c, MCAP);
    c_out = min(c, P);
  }
  const unsigned UMAX = 0xffffffffu;
  unsigned v0 = (lane < c_tot) ? csr[s + lane] : UMAX;
  unsigned v1 = (lane + 64 < c_tot) ? csr[s + 64 + lane] : UMAX;

  #pragma unroll
  for (int ph = 1; ph <= 7; ++ph) {
    int kk = 1 << ph;
    bool up = ((lane & (kk >> 1)) == 0);
    #pragma unroll
    for (int d = kk >> 1; d >= 2; d >>= 1) {
      int dl = d >> 1;
      unsigned p0 = __shfl_xor(v0, dl, 64);
      unsigned p1 = __shfl_xor(v1, dl, 64);
      bool low = ((lane & dl) == 0);
      if (low == up) { v0 = min(v0, p0); v1 = min(v1, p1); }
      else           { v0 = max(v0, p0); v1 = max(v1, p1); }
    }
    unsigned lo = min(v0, v1), hi = max(v0, v1);
    v0 = up ? lo : hi;
    v1 = up ? hi : lo;
  }

  int mys = lane >> 1, h = lane & 1;
  unsigned a0 = __shfl(v0, mys >> 1, 64);
  unsigned a1 = __shfl(v1, mys >> 1, 64);
  unsigned myidx = (mys & 1) ? a1 : a0;

  float a = 0.f, b = 0.f;
  if (mys < c_out) {
    const float* pp = pts + (size_t)myidx * 5;
    a = pp[1 + 2 * h];
    b = pp[2 + 2 * h];
  }
  floatx2 val = {a, b};
  __builtin_nontemporal_store(val, (floatx2*)(out + (size_t)k * (P * 4)) + lane);

  if (lane == 0) {
    out[OUT_CNT + k] = (float)c_out;
    int f = (k < nq) ? uniq[k] : NVOX;
    int cb = f / (GX * GY), rem = f % (GX * GY);
    out[OUT_COR + (size_t)k * 3 + 0] = (float)cb;
    out[OUT_COR + (size_t)k * 3 + 1] = (float)(rem / GY);
    out[OUT_COR + (size_t)k * 3 + 2] = (float)(rem % GY);
  }
}

// ======== fallback path C (proven R6): candidates voxel-major in d_out ====
__global__ void k_mark(const float* __restrict__ pts, int n,
                       int* __restrict__ occ, int* __restrict__ pflat) {
  int i = blockIdx.x * blockDim.x + threadIdx.x;
  if (i >= n) return;
  int flat = -1;
  if (point_voxel(pts + (size_t)i * 5, flat)) occ[flat] = 1;
  if (pflat) pflat[i] = flat;
}

__global__ void k_append(const int* __restrict__ pflat, int n,
                         const int* __restrict__ rank, int* __restrict__ cnt,
                         unsigned* __restrict__ vox) {
  int i = blockIdx.x * blockDim.x + threadIdx.x;
  if (i >= n) return;
  int f = pflat[i];
  if (f < 0) return;
  int v = rank[f];
  if (v >= K) return;
  int pos = atomicAdd(&cnt[v], 1);
  if (pos < MCAP) vox[(size_t)v * MCAP + pos] = (unsigned)i;
}

__global__ void k_append_fb(const float* __restrict__ pts, int n,
                            const int* __restrict__ rank, int* __restrict__ cnt,
                            unsigned* __restrict__ vox) {
  int i = blockIdx.x * blockDim.x + threadIdx.x;
  if (i >= n) return;
  int flat;
  if (!point_voxel(pts + (size_t)i * 5, flat)) return;
  int v = rank[flat];
  if (v >= K) return;
  int pos = atomicAdd(&cnt[v], 1);
  if (pos < MCAP) vox[(size_t)v * MCAP + pos] = (unsigned)i;
}

__global__ void __launch_bounds__(256) k_final_d(
    const float* __restrict__ pts, const int* __restrict__ uniq,
    const int* __restrict__ cnt, const int* __restrict__ nuq_p,
    float* __restrict__ out) {
  int wid = threadIdx.x >> 6, lane = threadIdx.x & 63;
  int k = blockIdx.x * 4 + wid;
  if (k >= K) return;
  int nuq = min(nuq_p[0], K);
  int c_tot = 0, c_out = 0;
  if (k < nuq) {
    int c = cnt[k];
    c_tot = min(c, MCAP);
    c_out = min(c, P);
  }
  const unsigned UMAX = 0xffffffffu;
  const unsigned* row = (const unsigned*)out + (size_t)k * MCAP;
  uint2 q = ((const uint2*)row)[lane];
  unsigned v0 = (2 * lane     < c_tot) ? q.x : UMAX;
  unsigned v1 = (2 * lane + 1 < c_tot) ? q.y : UMAX;
  #pragma unroll
  for (int ph = 1; ph <= 7; ++ph) {
    int kk = 1 << ph;
    bool up = ((lane & (kk >> 1)) == 0);
    #pragma unroll
    for (int d = kk >> 1; d >= 2; d >>= 1) {
      int dl = d >> 1;
      unsigned p0 = __shfl_xor(v0, dl, 64);
      unsigned p1 = __shfl_xor(v1, dl, 64);
      bool low = ((lane & dl) == 0);
      if (low == up) { v0 = min(v0, p0); v1 = min(v1, p1); }
      else           { v0 = max(v0, p0); v1 = max(v1, p1); }
    }
    unsigned lo = min(v0, v1), hi = max(v0, v1);
    v0 = up ? lo : hi;
    v1 = up ? hi : lo;
  }
  int mys = lane >> 1, h = lane & 1;
  unsigned a0 = __shfl(v0, mys >> 1, 64);
  unsigned a1 = __shfl(v1, mys >> 1, 64);
  unsigned myidx = (mys & 1) ? a1 : a0;
  float a = 0.f, b = 0.f;
  if (mys < c_out) {
    const float* pp = pts + (size_t)myidx * 5;
    a = pp[1 + 2 * h];
    b = pp[2 + 2 * h];
  }
  float2* vout = (float2*)(out + (size_t)k * (P * 4));
  vout[lane] = make_float2(a, b);
  if (lane == 0) {
    out[OUT_CNT + k] = (float)c_out;
    int f = (k < nuq) ? uniq[k] : NVOX;
    int cb = f / (GX * GY), rem = f % (GX * GY);
    out[OUT_COR + (size_t)k * 3 + 0] = (float)cb;
    out[OUT_COR + (size_t)k * 3 + 1] = (float)(rem / GY);
    out[OUT_COR + (size_t)k * 3 + 2] = (float)(rem % GY);
  }
}

}  // namespace

extern "C" void kernel_launch(void* const* d_in, const int* in_sizes, int n_in,
                              void* d_out, int out_size, void* d_ws, size_t ws_size,
                              hipStream_t stream) {
  const float* pts = (const float*)d_in[0];
  int n = in_sizes[0] / 5;
  float* out = (float*)d_out;
  int nb_pts = (n + 255) / 256;

  // ---- path A layout (ints) ----
  size_t o_occ   = 0;                                // OCC_PAD (becomes rank)
  size_t o_bsum  = o_occ + OCC_PAD;                  // NBLK+1
  size_t o_uniq  = o_bsum + NBLK + 1;                // K
  size_t o_voff  = o_uniq + K;                       // K
  size_t o_vcnt  = o_voff + K;                       // K
  size_t o_bcur  = o_vcnt + K;                       // NBUK2
  size_t o_arena = (o_bcur + NBUK2 + 3) & ~(size_t)3;// NBUK2*CAPB2 (records, then csr in-place)
  size_t totA    = o_arena + (size_t)NBUK2 * CAPB2;

  if (ws_size >= totA * sizeof(int) && n <= (1 << 21)) {
    int* occ   = (int*)d_ws + o_occ;
    int* bsum  = (int*)d_ws + o_bsum;
    int* uniq  = (int*)d_ws + o_uniq;
    int* voff  = (int*)d_ws + o_voff;
    int* vcnt  = (int*)d_ws + o_vcnt;
    int* bcur  = (int*)d_ws + o_bcur;
    unsigned* arena = (unsigned*)((int*)d_ws + o_arena);
    const int* nuq_p = bsum + NBLK;

    hipMemsetAsync(occ, 0, (size_t)OCC_PAD * sizeof(int), stream);
    hipMemsetAsync(bcur, 0, (size_t)NBUK2 * sizeof(int), stream);
    k_mark_bucket<<<(n + PPB - 1) / PPB, 256, 0, stream>>>(pts, n, occ, bcur, arena);
    k_bsum  <<<NBLK, 256, 0, stream>>>(occ, bsum);
    k_scanb <<<1, 1024, 0, stream>>>(bsum);
    k_rank  <<<NBLK, 256, 0, stream>>>(occ, bsum, uniq);
    k_build <<<NBUK2, 256, 0, stream>>>(arena, bcur, occ, voff, vcnt);
    k_final_csr<<<(K + 3) / 4, 256, 0, stream>>>(pts, arena, uniq, voff, vcnt, nuq_p, out);
  } else {
    // ---- path C (R6, proven): candidates voxel-major in d_out ----
    int* occ  = (int*)d_ws;
    int* bsum = occ + OCC_PAD;
    int* uniq = bsum + (NBLK + 1);
    int* cnt  = uniq + K;
    size_t base_ints = (size_t)OCC_PAD + (NBLK + 1) + K + K;
    base_ints = (base_ints + 3) & ~(size_t)3;
    int* pflat = (int*)d_ws + base_ints;
    bool use_pflat = ws_size >= (base_ints + (size_t)n) * sizeof(int);

    hipMemsetAsync(occ, 0, (size_t)OCC_PAD * sizeof(int), stream);
    hipMemsetAsync(cnt, 0, (size_t)K * sizeof(int), stream);
    k_mark  <<<nb_pts, 256, 0, stream>>>(pts, n, occ, use_pflat ? pflat : nullptr);
    k_bsum  <<<NBLK, 256, 0, stream>>>(occ, bsum);
    k_scanb <<<1, 1024, 0, stream>>>(bsum);
    k_rank  <<<NBLK, 256, 0, stream>>>(occ, bsum, uniq);
    if (use_pflat)
      k_append<<<nb_pts, 256, 0, stream>>>(pflat, n, occ, cnt, (unsigned*)out);
    else
      k_append_fb<<<nb_pts, 256, 0, stream>>>(pts, n, occ, cnt, (unsigned*)out);
    k_final_d<<<(K + 3) / 4, 256, 0, stream>>>(pts, uniq, cnt, bsum + NBLK, out);
  }
}